// Round 3
// baseline (751.995 us; speedup 1.0000x reference)
//
#include <hip/hip_runtime.h>
#include <hip/hip_bf16.h>

// ---------------------------------------------------------------------------
// GraphConv (DGL, norm='both', relu) x2, aggregate-first:
//   out = relu( (D_in^-1/2 A D_out^-1/2 X) @ W + b )
// Pipeline:
//   memset   : counters
//   hist     : out-degree via LDS packed-byte histogram (few fabric atomics)
//   bucket B1: edges -> 196 coarse dst-buckets (reg-stash, 1 atomic/block/bucket)
//   csr    B2: per-bucket LDS sort -> exact CSR (csr list, rs, deg), coalesced
//   wprep    : W -> bf16 W^T, chunk-tiled + XOR-swizzled global image
//   cast     : Xb = bf16(X * rsqrt(outdeg))
//   agg      : wave-per-node gather of Xb rows -> fp32 A rows in d_out
//   gemm x2  : bf16 MFMA, W staged via global_load_lds (pre-swizzled),
//              A staged fp32->bf16 swizzled ds_write_b64, bias+relu, in-place
// ---------------------------------------------------------------------------

typedef __attribute__((ext_vector_type(8))) short short8;
typedef __attribute__((ext_vector_type(4))) float f32x4;

static __device__ __forceinline__ ushort f2b(float f) {
    __hip_bfloat16 h = __float2bfloat16(f);
    return *reinterpret_cast<ushort*>(&h);
}
static __device__ __forceinline__ float b2f(ushort u) {
    union { unsigned int i; float f; } c;
    c.i = ((unsigned int)u) << 16;
    return c.f;
}

static __device__ __forceinline__ void gld_lds16(const void* g, void* l) {
    __builtin_amdgcn_global_load_lds(
        (const __attribute__((address_space(1))) unsigned int*)g,
        (__attribute__((address_space(3))) unsigned int*)l, 16, 0, 0);
}

// ---------------- out-degree: LDS packed-byte histogram --------------------
__global__ __launch_bounds__(256) void hist_kernel(
    const int* __restrict__ src_c, int Ec, int* cnt_c,
    const int* __restrict__ src_d, int Ed, int* cnt_d,
    int N, int Hc, int Hd)
{
    __shared__ unsigned int bins[12544];   // ceil(50176/4) bytes bins
    int nb = (N + 3) >> 2;
    for (int i = threadIdx.x; i < nb; i += 256) bins[i] = 0u;
    __syncthreads();

    const int* src; int E, b, H; int* cnt;
    if ((int)blockIdx.x < Hc) { src = src_c; E = Ec; cnt = cnt_c; b = blockIdx.x; H = Hc; }
    else { src = src_d; E = Ed; cnt = cnt_d; b = blockIdx.x - Hc; H = Hd; }

    int lo = (int)((long long)E * b / H);
    int hi = (int)((long long)E * (b + 1) / H);
    for (int i = lo + threadIdx.x; i < hi; i += 256) {
        int v = src[i];
        atomicAdd(&bins[v >> 2], 1u << ((v & 3) * 8));
    }
    __syncthreads();
    for (int i = threadIdx.x; i < nb; i += 256) {
        unsigned int u = bins[i];
        if (!u) continue;
        int v0 = i * 4;
        if (u & 0x000000ffu) atomicAdd(&cnt[v0 + 0], (int)(u & 0xff));
        if (u & 0x0000ff00u) atomicAdd(&cnt[v0 + 1], (int)((u >> 8) & 0xff));
        if (u & 0x00ff0000u) atomicAdd(&cnt[v0 + 2], (int)((u >> 16) & 0xff));
        if (u & 0xff000000u) atomicAdd(&cnt[v0 + 3], (int)(u >> 24));
    }
}

// ---------------- B1: bucket edges by dst>>8 -------------------------------
#define EPB 4096
__global__ __launch_bounds__(256) void bucket_kernel(
    const int* __restrict__ src_c, const int* __restrict__ dst_c, int Ec,
    int* gf_c, int* bbuf_c, int capc,
    const int* __restrict__ src_d, const int* __restrict__ dst_d, int Ed,
    int* gf_d, int* bbuf_d, int capd, int nb1c)
{
    __shared__ int cnt[256], base[256];
    const int* src; const int* dst; int E; int* gf; int* bbuf; int cap; int e0;
    if ((int)blockIdx.x < nb1c) {
        src = src_c; dst = dst_c; E = Ec; gf = gf_c; bbuf = bbuf_c; cap = capc;
        e0 = blockIdx.x * EPB;
    } else {
        src = src_d; dst = dst_d; E = Ed; gf = gf_d; bbuf = bbuf_d; cap = capd;
        e0 = (blockIdx.x - nb1c) * EPB;
    }
    cnt[threadIdx.x] = 0; base[threadIdx.x] = 0;
    __syncthreads();

    int sv[EPB / 256], dv[EPB / 256];
    int n = 0;
#pragma unroll
    for (int r = 0; r < EPB / 256; ++r) {
        int e = e0 + r * 256 + threadIdx.x;
        if (e < E) { dv[r] = dst[e]; sv[r] = src[e]; atomicAdd(&cnt[dv[r] >> 8], 1); n = r + 1; }
    }
    __syncthreads();
    int c = cnt[threadIdx.x];
    if (c) base[threadIdx.x] = atomicAdd(&gf[threadIdx.x], c);
    cnt[threadIdx.x] = 0;
    __syncthreads();
    for (int r = 0; r < n; ++r) {
        int b = dv[r] >> 8;
        int pos = base[b] + atomicAdd(&cnt[b], 1);
        if (pos < cap) bbuf[(size_t)b * cap + pos] = (sv[r] << 8) | (dv[r] & 255);
    }
}

// ---------------- B2: per-bucket LDS sort -> exact CSR ---------------------
#define CAPMAX 8960
__global__ __launch_bounds__(256) void csr_kernel(
    int* bbuf_c, const int* __restrict__ gf_c, int capc, int* rs_c, int* dg_c,
    int* bbuf_d, const int* __restrict__ gf_d, int capd, int* rs_d, int* dg_d,
    int N, int nbktc)
{
    __shared__ int pk[CAPMAX];
    __shared__ int h[256], st[256], ex[256];
    int* bbuf; const int* gf; int cap; int* rs; int* dg; int b;
    if ((int)blockIdx.x < nbktc) {
        b = blockIdx.x; bbuf = bbuf_c; gf = gf_c; cap = capc; rs = rs_c; dg = dg_c;
    } else {
        b = blockIdx.x - nbktc; bbuf = bbuf_d; gf = gf_d; cap = capd; rs = rs_d; dg = dg_d;
    }
    const int tid = threadIdx.x;
    int m = gf[b]; if (m > cap) m = cap;
    int* reg = bbuf + (size_t)b * cap;

    h[tid] = 0;
    __syncthreads();
    for (int i = tid; i < m; i += 256) { int p = reg[i]; pk[i] = p; atomicAdd(&h[p & 255], 1); }
    __syncthreads();
    int x = h[tid];
    st[tid] = x;
    __syncthreads();
    for (int off = 1; off < 256; off <<= 1) {
        int t = 0;
        if (tid >= off) t = st[tid - off];
        __syncthreads();
        if (tid >= off) st[tid] += t;
        __syncthreads();
    }
    ex[tid] = st[tid] - x;  // exclusive scan
    int vg = b * 256 + tid;
    if (vg < N) { rs[vg] = b * cap + ex[tid]; dg[vg] = x; }
    h[tid] = 0;
    __syncthreads();
    for (int i = tid; i < m; i += 256) {
        int p = pk[i]; int v = p & 255;
        int r = atomicAdd(&h[v], 1);
        reg[ex[v] + r] = p >> 8;   // src id
    }
}

// ---------------- W prep: bf16 W^T, chunk-tiled + swizzled image -----------
// image (per graph, chunks of BK): 16B block (n, slot) holds
//   W[kc + ((slot^(n&7))*8 + j)][n], j=0..7
__global__ __launch_bounds__(256) void wprep_kernel(
    const float* __restrict__ Wc, const float* __restrict__ Wd,
    ushort* __restrict__ Wtc, ushort* __restrict__ Wtd)
{
    int t = blockIdx.x * 256 + threadIdx.x;
    ushort o[8];
    if (t < 2048) {            // graph c: K=BN=BK=128, 1 chunk, 128 n x 16 slots
        int n = t >> 4, slot = t & 15;
        int k0 = (slot ^ (n & 7)) << 3;
#pragma unroll
        for (int j = 0; j < 8; ++j) o[j] = f2b(Wc[(k0 + j) * 128 + n]);
        uint4 v;
        v.x = (unsigned)o[0] | ((unsigned)o[1] << 16);
        v.y = (unsigned)o[2] | ((unsigned)o[3] << 16);
        v.z = (unsigned)o[4] | ((unsigned)o[5] << 16);
        v.w = (unsigned)o[6] | ((unsigned)o[7] << 16);
        *(uint4*)&Wtc[n * 128 + slot * 8] = v;
    } else if (t < 2048 + 8192) {  // graph d: K=BN=256, BK=64, 4 chunks, 256 n x 8 slots
        int tt = t - 2048;
        int ci = tt >> 11, r = tt & 2047;
        int n = r >> 3, slot = r & 7;
        int k0 = ci * 64 + ((slot ^ (n & 7)) << 3);
#pragma unroll
        for (int j = 0; j < 8; ++j) o[j] = f2b(Wd[(k0 + j) * 256 + n]);
        uint4 v;
        v.x = (unsigned)o[0] | ((unsigned)o[1] << 16);
        v.y = (unsigned)o[2] | ((unsigned)o[3] << 16);
        v.z = (unsigned)o[4] | ((unsigned)o[5] << 16);
        v.w = (unsigned)o[6] | ((unsigned)o[7] << 16);
        *(uint4*)&Wtd[ci * 16384 + n * 64 + slot * 8] = v;
    }
}

// ---------------- cast + out-norm scale to bf16 (both graphs) --------------
__global__ __launch_bounds__(256) void cast_kernel(
    const float* __restrict__ Xc, const int* __restrict__ coc, ushort* __restrict__ Xbc,
    const float* __restrict__ Xd, const int* __restrict__ cod, ushort* __restrict__ Xbd,
    int N, int nbc)
{
    const float* X; const int* co; ushort* Xb; int C4, t;
    if ((int)blockIdx.x < nbc) { X = Xc; co = coc; Xb = Xbc; C4 = 32; t = blockIdx.x * 256 + threadIdx.x; }
    else { X = Xd; co = cod; Xb = Xbd; C4 = 64; t = (blockIdx.x - nbc) * 256 + threadIdx.x; }
    if (t >= N * C4) return;
    int row = t / C4, c4 = t % C4;
    int od = co[row]; if (od < 1) od = 1;
    float nr = rsqrtf((float)od);
    float4 xv = ((const float4*)(X + (size_t)row * (C4 * 4)))[c4];
    ushort4 o;
    o.x = f2b(xv.x * nr); o.y = f2b(xv.y * nr);
    o.z = f2b(xv.z * nr); o.w = f2b(xv.w * nr);
    ((ushort4*)(Xb + (size_t)row * (C4 * 4)))[c4] = o;
}

// ---------------- aggregation (bf16 rows, pre-scaled), exact CSR -----------
template <int VEC>
static __device__ __forceinline__ void agg_node(
    const ushort* __restrict__ Xb, const int* __restrict__ rs,
    const int* __restrict__ dg, const int* __restrict__ csr,
    float* __restrict__ out, int w, int lane, int N)
{
    constexpr int D = VEC * 64;
    if (w >= N) return;
    int beg = rs[w], deg = dg[w];
    float acc[VEC];
#pragma unroll
    for (int k = 0; k < VEC; ++k) acc[k] = 0.f;
    const int* rowp = csr + beg;

    for (int base = 0; base < deg; base += 64) {
        int m = deg - base; if (m > 64) m = 64;
        int u_l = (lane < m) ? rowp[base + lane] : 0;
#pragma unroll 4
        for (int j = 0; j < m; ++j) {
            int u = __shfl(u_l, j);
            const ushort* xr = Xb + (size_t)u * D + lane * VEC;
            if constexpr (VEC == 2) {
                unsigned int xv = *(const unsigned int*)xr;
                acc[0] += b2f((ushort)(xv & 0xffff));
                acc[1] += b2f((ushort)(xv >> 16));
            } else {
                uint2 xv = *(const uint2*)xr;
                acc[0] += b2f((ushort)(xv.x & 0xffff));
                acc[1] += b2f((ushort)(xv.x >> 16));
                acc[2] += b2f((ushort)(xv.y & 0xffff));
                acc[3] += b2f((ushort)(xv.y >> 16));
            }
        }
    }
    int id = deg < 1 ? 1 : deg;
    float nd = rsqrtf((float)id);
    float* orow = out + (size_t)w * D + lane * VEC;
    if constexpr (VEC == 2) {
        float2 o; o.x = acc[0] * nd; o.y = acc[1] * nd;
        *(float2*)orow = o;
    } else {
        float4 o; o.x = acc[0] * nd; o.y = acc[1] * nd;
        o.z = acc[2] * nd; o.w = acc[3] * nd;
        *(float4*)orow = o;
    }
}

__global__ __launch_bounds__(256) void agg_kernel2(
    const ushort* __restrict__ Xbc, const int* __restrict__ rsc,
    const int* __restrict__ dgc, const int* __restrict__ csrc, float* outc,
    const ushort* __restrict__ Xbd, const int* __restrict__ rsd,
    const int* __restrict__ dgd, const int* __restrict__ csrd, float* outd,
    int N, int abc)
{
    int lane = threadIdx.x & 63;
    if ((int)blockIdx.x < abc) {
        int w = (blockIdx.x * 256 + threadIdx.x) >> 6;
        agg_node<2>(Xbc, rsc, dgc, csrc, outc, w, lane, N);
    } else {
        int w = ((blockIdx.x - abc) * 256 + threadIdx.x) >> 6;
        agg_node<4>(Xbd, rsd, dgd, csrd, outd, w, lane, N);
    }
}

// ---------------- bf16 MFMA GEMM + bias + relu, in-place -------------------
// A: fp32 [M][K] (== O, in-place safe: staged before writes)
// Wt: pre-swizzled bf16 W^T chunk image in global (ws)
template <int K, int BN, int BK>
__global__ __launch_bounds__(256) void gemm2_kernel(
    const float* A, const ushort* __restrict__ Wt,
    const float* __restrict__ bias, float* O, int M)
{
    constexpr int BM = 64;
    constexpr int HN = BN / 2;
    constexpr int NC = HN / 16;
    constexpr int C4 = K / 4;
    __shared__ ushort Als[BM * K];
    __shared__ ushort Wts[BN * BK];

    const int tid = threadIdx.x;
    const int lane = tid & 63, wid = tid >> 6;
    const int wr = wid >> 1, wc = wid & 1;
    const int lr = lane & 15, lk8 = (lane >> 4) * 8;
    const int row0 = blockIdx.x * BM;

    f32x4 acc[2][NC];
#pragma unroll
    for (int mr = 0; mr < 2; ++mr)
#pragma unroll
        for (int nc = 0; nc < NC; ++nc) acc[mr][nc] = (f32x4)0.f;

    // stage A tile, fp32 -> bf16, XOR-swizzled (slot ^= row&7)
    for (int i = tid; i < BM * C4; i += 256) {
        int r = i / C4, c4 = i % C4;
        int row = row0 + r;
        float4 x = make_float4(0.f, 0.f, 0.f, 0.f);
        if (row < M) x = *(const float4*)(A + (size_t)row * K + c4 * 4);
        ushort4 o;
        o.x = f2b(x.x); o.y = f2b(x.y); o.z = f2b(x.z); o.w = f2b(x.w);
        int slot = (c4 >> 1) ^ (r & 7);
        *(ushort4*)&Als[r * K + slot * 8 + (c4 & 1) * 4] = o;
    }

    for (int ci = 0; ci < K / BK; ++ci) {
        if (ci) __syncthreads();   // prior MFMA reads of Wts done
        // stage W chunk: pre-swizzled image, direct global->LDS (linear)
        constexpr int NL = BN * BK * 2 / (256 * 16);
        const ushort* wsrc = Wt + ci * (BN * BK);
#pragma unroll
        for (int it = 0; it < NL; ++it) {
            int off16 = it * 256 + tid;
            gld_lds16(&wsrc[off16 * 8], &Wts[off16 * 8]);
        }
        __syncthreads();           // drains vmcnt (global_load_lds) + lgkm

#pragma unroll
        for (int k0 = 0; k0 < BK; k0 += 32) {
            short8 a[2], bfr[NC];
#pragma unroll
            for (int mr = 0; mr < 2; ++mr) {
                int r = wr * 32 + mr * 16 + lr;
                int k = ci * BK + k0 + lk8;
                int slot = (k >> 3) ^ (r & 7);
                a[mr] = *(const short8*)&Als[r * K + slot * 8];
            }
#pragma unroll
            for (int nc = 0; nc < NC; ++nc) {
                int n = wc * HN + nc * 16 + lr;
                int kk = k0 + lk8;
                int slot = (kk >> 3) ^ (n & 7);
                bfr[nc] = *(const short8*)&Wts[n * BK + slot * 8];
            }
#pragma unroll
            for (int mr = 0; mr < 2; ++mr)
#pragma unroll
                for (int nc = 0; nc < NC; ++nc)
                    acc[mr][nc] = __builtin_amdgcn_mfma_f32_16x16x32_bf16(
                        a[mr], bfr[nc], acc[mr][nc], 0, 0, 0);
        }
    }

    // epilogue: bias + relu (C/D: col=lane&15, row=(lane>>4)*4+reg)
#pragma unroll
    for (int mr = 0; mr < 2; ++mr)
#pragma unroll
        for (int nc = 0; nc < NC; ++nc) {
            int col = wc * HN + nc * 16 + lr;
            float bv = bias[col];
#pragma unroll
            for (int r = 0; r < 4; ++r) {
                int row = row0 + wr * 32 + mr * 16 + (lane >> 4) * 4 + r;
                if (row < M)
                    O[(size_t)row * BN + col] = fmaxf(acc[mr][nc][r] + bv, 0.f);
            }
        }
}

// ---------------------------------------------------------------------------
extern "C" void kernel_launch(void* const* d_in, const int* in_sizes, int n_in,
                              void* d_out, int out_size, void* d_ws, size_t ws_size,
                              hipStream_t stream)
{
    const float* feat_c = (const float*)d_in[0];
    const float* feat_d = (const float*)d_in[1];
    const int* src_c = (const int*)d_in[2];
    const int* dst_c = (const int*)d_in[3];
    const int* src_d = (const int*)d_in[4];
    const int* dst_d = (const int*)d_in[5];
    const float* W_c = (const float*)d_in[6];
    const float* b_c = (const float*)d_in[7];
    const float* W_d = (const float*)d_in[8];
    const float* b_d = (const float*)d_in[9];

    const int D_c = in_sizes[7];          // 128
    const int D_d = in_sizes[9];          // 256
    const int N = in_sizes[0] / D_c;      // 50000
    const int E_c = in_sizes[2];
    const int E_d = in_sizes[4];

    float* out_c = (float*)d_out;
    float* out_d = (float*)d_out + (size_t)N * D_c;

    const int NBKT = (N + 255) >> 8;      // 196
    // bucket caps: mean + ~8 sigma, clamped to LDS capacity
    int capc = E_c / NBKT; capc += 8 * (int)sqrtf((float)capc) + 32; capc = (capc + 15) & ~15;
    int capd = E_d / NBKT; capd += 8 * (int)sqrtf((float)capd) + 32; capd = (capd + 15) & ~15;
    if (capc > CAPMAX) capc = CAPMAX;
    if (capd > CAPMAX) capd = CAPMAX;

    // workspace layout
    int* ws = (int*)d_ws;
    int* cnt_out_c = ws;                         // N
    int* cnt_out_d = ws + N;                     // N
    int* gf_c = ws + 2 * (size_t)N;              // 256
    int* gf_d = gf_c + 256;                      // 256
    ushort* Wt_c = (ushort*)(gf_d + 256);        // 128*128
    ushort* Wt_d = Wt_c + 16384;                 // 256*256
    int* bbuf_c = (int*)(Wt_d + 65536);          // NBKT*capc
    int* bbuf_d = bbuf_c + (size_t)NBKT * capc;  // NBKT*capd
    int* rs_c = bbuf_d + (size_t)NBKT * capd;    // N
    int* dg_c = rs_c + N;                        // N
    int* rs_d = dg_c + N;                        // N
    int* dg_d = rs_d + N;                        // N
    ushort* Xb_c = (ushort*)(dg_d + N);          // N*128
    ushort* Xb_d = Xb_c + (size_t)N * D_c;       // N*256

    hipMemsetAsync(ws, 0, (2 * (size_t)N + 512) * sizeof(int), stream);

    // out-degree histogram
    const int Hc = 8, Hd = 4;
    hist_kernel<<<Hc + Hd, 256, 0, stream>>>(src_c, E_c, cnt_out_c,
                                             src_d, E_d, cnt_out_d, N, Hc, Hd);

    // B1: coarse bucketing
    int nb1c = (E_c + EPB - 1) / EPB, nb1d = (E_d + EPB - 1) / EPB;
    bucket_kernel<<<nb1c + nb1d, 256, 0, stream>>>(
        src_c, dst_c, E_c, gf_c, bbuf_c, capc,
        src_d, dst_d, E_d, gf_d, bbuf_d, capd, nb1c);

    // B2: per-bucket CSR
    csr_kernel<<<2 * NBKT, 256, 0, stream>>>(
        bbuf_c, gf_c, capc, rs_c, dg_c,
        bbuf_d, gf_d, capd, rs_d, dg_d, N, NBKT);

    // W prep (independent; before gemm)
    wprep_kernel<<<40, 256, 0, stream>>>(W_c, W_d, Wt_c, Wt_d);

    // cast + scale
    int nbc = (N * (D_c / 4) + 255) / 256, nbd = (N * (D_d / 4) + 255) / 256;
    cast_kernel<<<nbc + nbd, 256, 0, stream>>>(feat_c, cnt_out_c, Xb_c,
                                               feat_d, cnt_out_d, Xb_d, N, nbc);

    // aggregation (wave per node)
    int abc = (N + 3) / 4;
    agg_kernel2<<<2 * abc, 256, 0, stream>>>(Xb_c, rs_c, dg_c, bbuf_c, out_c,
                                             Xb_d, rs_d, dg_d, bbuf_d, out_d, N, abc);

    // GEMMs (in-place on d_out)
    int gb = (N + 63) / 64;
    gemm2_kernel<128, 128, 128><<<gb, 256, 0, stream>>>(out_c, Wt_c, b_c, out_c, N);
    gemm2_kernel<256, 256, 64><<<gb, 256, 0, stream>>>(out_d, Wt_d, b_d, out_d, N);
}

// Round 4
// 417.996 us; speedup vs baseline: 1.7990x; 1.7990x over previous
//
#include <hip/hip_runtime.h>
#include <hip/hip_bf16.h>

// ---------------------------------------------------------------------------
// GraphConv (DGL, norm='both', relu) x2, aggregate-first:
//   out = relu( (D_in^-1/2 A D_out^-1/2 X) @ W + b )
// Pipeline (all fabric scatters write-combined via in-LDS chunk sort):
//   memset : 4 bucket-cursor arrays (4KB)
//   wprep  : W -> bf16 W^T chunk-tiled + XOR-swizzled global image
//   part   : edges -> 196 coarse buckets, 4 channels (c/d x dst/src).
//            Per 4096-edge chunk: LDS hist+scan+scatter, then run-coalesced
//            flush (1 global atomic per block-bucket, runs avg ~21 ints).
//   b2s    : per src-bucket 256-bin LDS count -> out-degree (no memset need)
//   cast   : Xb = bf16(X * rsqrt(outdeg))
//   b2d    : per dst-bucket LDS sort -> CSR written back LINEARLY + rs/deg
//   agg    : wave-per-node gather of Xb rows -> fp32 A rows in d_out
//   gemm x2: bf16 MFMA, pre-swizzled W via global_load_lds, swizzled A LDS,
//            bias+relu epilogue, in-place on d_out
// ---------------------------------------------------------------------------

typedef __attribute__((ext_vector_type(8))) short short8;
typedef __attribute__((ext_vector_type(4))) float f32x4;

#define RND 4096      // edges per partition chunk
#define CAPMAX 8960   // max bucket capacity (LDS sort limit)

static __device__ __forceinline__ ushort f2b(float f) {
    __hip_bfloat16 h = __float2bfloat16(f);
    return *reinterpret_cast<ushort*>(&h);
}
static __device__ __forceinline__ float b2f(ushort u) {
    union { unsigned int i; float f; } c;
    c.i = ((unsigned int)u) << 16;
    return c.f;
}
static __device__ __forceinline__ void gld_lds16(const void* g, void* l) {
    __builtin_amdgcn_global_load_lds(
        (const __attribute__((address_space(1))) unsigned int*)g,
        (__attribute__((address_space(3))) unsigned int*)l, 16, 0, 0);
}

// ---------------- part: 4-channel chunk partition with WC flush ------------
// channel payloads: dst-keyed -> (src<<8)|(dst&255); src-keyed -> src
__global__ __launch_bounds__(256) void part_kernel(
    const int* __restrict__ src_c, const int* __restrict__ dst_c, int Ec, int Rc,
    const int* __restrict__ src_d, const int* __restrict__ dst_d, int Ed, int Rd,
    int* gf_cd, int* gf_cs, int* gf_dd, int* gf_ds,
    int* dbuf_c, int* sbuf_c, int* dbuf_d, int* sbuf_d, int capc, int capd)
{
    __shared__ int pk[RND];
    __shared__ unsigned char pb[RND];
    __shared__ int hist[256], st[256], ex2[256], cur[256], gbase[256];

    const int tid = threadIdx.x;
    const int bid = blockIdx.x;
    const int* keys; const int* pays; int E; int* gf; int* buf; int cap; int e0;
    if (bid < Rc)            { keys = dst_c; pays = src_c; E = Ec; gf = gf_cd; buf = dbuf_c; cap = capc; e0 = bid * RND; }
    else if (bid < 2 * Rc)   { keys = src_c; pays = 0;     E = Ec; gf = gf_cs; buf = sbuf_c; cap = capc; e0 = (bid - Rc) * RND; }
    else if (bid < 2 * Rc + Rd) { keys = dst_d; pays = src_d; E = Ed; gf = gf_dd; buf = dbuf_d; cap = capd; e0 = (bid - 2 * Rc) * RND; }
    else                     { keys = src_d; pays = 0;     E = Ed; gf = gf_ds; buf = sbuf_d; cap = capd; e0 = (bid - 2 * Rc - Rd) * RND; }

    hist[tid] = 0;
    __syncthreads();

    int kb[RND / 256], pv[RND / 256];
    int n = 0;
#pragma unroll
    for (int r = 0; r < RND / 256; ++r) {
        int e = e0 + r * 256 + tid;
        if (e < E) {
            int k = keys[e];
            pv[r] = pays ? ((pays[e] << 8) | (k & 255)) : k;
            kb[r] = k >> 8;
            atomicAdd(&hist[kb[r]], 1);
            n = r + 1;
        }
    }
    __syncthreads();

    int x = hist[tid];
    st[tid] = x;
    __syncthreads();
    for (int off = 1; off < 256; off <<= 1) {
        int t2 = 0;
        if (tid >= off) t2 = st[tid - off];
        __syncthreads();
        if (tid >= off) st[tid] += t2;
        __syncthreads();
    }
    ex2[tid] = st[tid] - x;
    cur[tid] = st[tid] - x;
    __syncthreads();

    for (int r = 0; r < n; ++r) {
        int slot = atomicAdd(&cur[kb[r]], 1);
        pk[slot] = pv[r];
        pb[slot] = (unsigned char)kb[r];
    }
    if (x) gbase[tid] = atomicAdd(&gf[tid], x);
    __syncthreads();

    int m = st[255];
    for (int i = tid; i < m; i += 256) {
        int b = pb[i];
        int pos = gbase[b] + (i - ex2[b]);
        if (pos < cap) buf[(size_t)b * cap + pos] = pk[i];
    }
}

// ---------------- b2s: per src-bucket count -> out-degree ------------------
__global__ __launch_bounds__(256) void b2s_kernel(
    const int* __restrict__ sbuf_c, const int* __restrict__ gf_cs, int capc, int* cnt_c,
    const int* __restrict__ sbuf_d, const int* __restrict__ gf_ds, int capd, int* cnt_d,
    int N, int NBKT)
{
    __shared__ int h[256];
    const int tid = threadIdx.x;
    const int* sbuf; const int* gf; int cap; int* cnt; int bb;
    if ((int)blockIdx.x < NBKT) { sbuf = sbuf_c; gf = gf_cs; cap = capc; cnt = cnt_c; bb = blockIdx.x; }
    else { sbuf = sbuf_d; gf = gf_ds; cap = capd; cnt = cnt_d; bb = blockIdx.x - NBKT; }
    h[tid] = 0;
    __syncthreads();
    int m = gf[bb]; if (m > cap) m = cap;
    const int* reg = sbuf + (size_t)bb * cap;
    for (int i = tid; i < m; i += 256) atomicAdd(&h[reg[i] & 255], 1);
    __syncthreads();
    int v = bb * 256 + tid;
    if (v < N) cnt[v] = h[tid];
}

// ---------------- b2d: per dst-bucket LDS sort -> linear CSR + rs/deg ------
__global__ __launch_bounds__(256) void b2d_kernel(
    int* dbuf_c, const int* __restrict__ gf_cd, int capc, int* rs_c, int* dg_c,
    int* dbuf_d, const int* __restrict__ gf_dd, int capd, int* rs_d, int* dg_d,
    int N, int NBKT)
{
    __shared__ int pk[CAPMAX];
    __shared__ int h[256], st[256], ex2[256], cur[256];
    const int tid = threadIdx.x;
    int* bbuf; const int* gf; int cap; int* rs; int* dg; int bb;
    if ((int)blockIdx.x < NBKT) { bbuf = dbuf_c; gf = gf_cd; cap = capc; rs = rs_c; dg = dg_c; bb = blockIdx.x; }
    else { bbuf = dbuf_d; gf = gf_dd; cap = capd; rs = rs_d; dg = dg_d; bb = blockIdx.x - NBKT; }

    int m = gf[bb]; if (m > cap) m = cap;
    int* reg = bbuf + (size_t)bb * cap;

    h[tid] = 0;
    __syncthreads();
    for (int i = tid; i < m; i += 256) atomicAdd(&h[reg[i] & 255], 1);
    __syncthreads();
    int x = h[tid];
    st[tid] = x;
    __syncthreads();
    for (int off = 1; off < 256; off <<= 1) {
        int t2 = 0;
        if (tid >= off) t2 = st[tid - off];
        __syncthreads();
        if (tid >= off) st[tid] += t2;
        __syncthreads();
    }
    int ex_t = st[tid] - x;
    ex2[tid] = ex_t;
    cur[tid] = ex_t;
    int v = bb * 256 + tid;
    if (v < N) { rs[v] = bb * cap + ex_t; dg[v] = x; }
    __syncthreads();
    for (int i = tid; i < m; i += 256) {
        int p = reg[i];
        int slot = atomicAdd(&cur[p & 255], 1);
        pk[slot] = p >> 8;   // src id, sorted by dst
    }
    __syncthreads();
    for (int i = tid; i < m; i += 256) reg[i] = pk[i];  // linear, coalesced
}

// ---------------- W prep: bf16 W^T chunk-tiled + swizzled image ------------
__global__ __launch_bounds__(256) void wprep_kernel(
    const float* __restrict__ Wc, const float* __restrict__ Wd,
    ushort* __restrict__ Wtc, ushort* __restrict__ Wtd)
{
    int t = blockIdx.x * 256 + threadIdx.x;
    ushort o[8];
    if (t < 2048) {            // c: K=BN=BK=128: 128 n x 16 slots
        int n = t >> 4, slot = t & 15;
        int k0 = (slot ^ (n & 7)) << 3;
#pragma unroll
        for (int j = 0; j < 8; ++j) o[j] = f2b(Wc[(k0 + j) * 128 + n]);
        uint4 vv;
        vv.x = (unsigned)o[0] | ((unsigned)o[1] << 16);
        vv.y = (unsigned)o[2] | ((unsigned)o[3] << 16);
        vv.z = (unsigned)o[4] | ((unsigned)o[5] << 16);
        vv.w = (unsigned)o[6] | ((unsigned)o[7] << 16);
        *(uint4*)&Wtc[n * 128 + slot * 8] = vv;
    } else if (t < 2048 + 8192) {  // d: K=BN=256, BK=64: 4 chunks x 256 n x 8 slots
        int tt = t - 2048;
        int ci = tt >> 11, r = tt & 2047;
        int n = r >> 3, slot = r & 7;
        int k0 = ci * 64 + ((slot ^ (n & 7)) << 3);
#pragma unroll
        for (int j = 0; j < 8; ++j) o[j] = f2b(Wd[(k0 + j) * 256 + n]);
        uint4 vv;
        vv.x = (unsigned)o[0] | ((unsigned)o[1] << 16);
        vv.y = (unsigned)o[2] | ((unsigned)o[3] << 16);
        vv.z = (unsigned)o[4] | ((unsigned)o[5] << 16);
        vv.w = (unsigned)o[6] | ((unsigned)o[7] << 16);
        *(uint4*)&Wtd[ci * 16384 + n * 64 + slot * 8] = vv;
    }
}

// ---------------- cast + out-norm scale to bf16 ----------------------------
__global__ __launch_bounds__(256) void cast_kernel(
    const float* __restrict__ Xc, const int* __restrict__ coc, ushort* __restrict__ Xbc,
    const float* __restrict__ Xd, const int* __restrict__ cod, ushort* __restrict__ Xbd,
    int N, int nbc)
{
    const float* X; const int* co; ushort* Xb; int C4, t;
    if ((int)blockIdx.x < nbc) { X = Xc; co = coc; Xb = Xbc; C4 = 32; t = blockIdx.x * 256 + threadIdx.x; }
    else { X = Xd; co = cod; Xb = Xbd; C4 = 64; t = (blockIdx.x - nbc) * 256 + threadIdx.x; }
    if (t >= N * C4) return;
    int row = t / C4, c4 = t % C4;
    int od = co[row]; if (od < 1) od = 1;
    float nr = rsqrtf((float)od);
    float4 xv = ((const float4*)(X + (size_t)row * (C4 * 4)))[c4];
    ushort4 o;
    o.x = f2b(xv.x * nr); o.y = f2b(xv.y * nr);
    o.z = f2b(xv.z * nr); o.w = f2b(xv.w * nr);
    ((ushort4*)(Xb + (size_t)row * (C4 * 4)))[c4] = o;
}

// ---------------- aggregation (bf16 rows, pre-scaled), exact CSR -----------
template <int VEC>
static __device__ __forceinline__ void agg_node(
    const ushort* __restrict__ Xb, const int* __restrict__ rs,
    const int* __restrict__ dg, const int* __restrict__ csr,
    float* __restrict__ out, int w, int lane, int N)
{
    constexpr int D = VEC * 64;
    if (w >= N) return;
    int beg = rs[w], deg = dg[w];
    float acc[VEC];
#pragma unroll
    for (int k = 0; k < VEC; ++k) acc[k] = 0.f;
    const int* rowp = csr + beg;

    for (int base = 0; base < deg; base += 64) {
        int m = deg - base; if (m > 64) m = 64;
        int u_l = (lane < m) ? rowp[base + lane] : 0;
#pragma unroll 4
        for (int j = 0; j < m; ++j) {
            int u = __shfl(u_l, j);
            const ushort* xr = Xb + (size_t)u * D + lane * VEC;
            if constexpr (VEC == 2) {
                unsigned int xv = *(const unsigned int*)xr;
                acc[0] += b2f((ushort)(xv & 0xffff));
                acc[1] += b2f((ushort)(xv >> 16));
            } else {
                uint2 xv = *(const uint2*)xr;
                acc[0] += b2f((ushort)(xv.x & 0xffff));
                acc[1] += b2f((ushort)(xv.x >> 16));
                acc[2] += b2f((ushort)(xv.y & 0xffff));
                acc[3] += b2f((ushort)(xv.y >> 16));
            }
        }
    }
    int id = deg < 1 ? 1 : deg;
    float nd = rsqrtf((float)id);
    float* orow = out + (size_t)w * D + lane * VEC;
    if constexpr (VEC == 2) {
        float2 o; o.x = acc[0] * nd; o.y = acc[1] * nd;
        *(float2*)orow = o;
    } else {
        float4 o; o.x = acc[0] * nd; o.y = acc[1] * nd;
        o.z = acc[2] * nd; o.w = acc[3] * nd;
        *(float4*)orow = o;
    }
}

__global__ __launch_bounds__(256) void agg_kernel2(
    const ushort* __restrict__ Xbc, const int* __restrict__ rsc,
    const int* __restrict__ dgc, const int* __restrict__ csrc, float* outc,
    const ushort* __restrict__ Xbd, const int* __restrict__ rsd,
    const int* __restrict__ dgd, const int* __restrict__ csrd, float* outd,
    int N, int abc)
{
    int lane = threadIdx.x & 63;
    if ((int)blockIdx.x < abc) {
        int w = (blockIdx.x * 256 + threadIdx.x) >> 6;
        agg_node<2>(Xbc, rsc, dgc, csrc, outc, w, lane, N);
    } else {
        int w = ((blockIdx.x - abc) * 256 + threadIdx.x) >> 6;
        agg_node<4>(Xbd, rsd, dgd, csrd, outd, w, lane, N);
    }
}

// ---------------- bf16 MFMA GEMM + bias + relu, in-place -------------------
template <int K, int BN, int BK>
__global__ __launch_bounds__(256) void gemm2_kernel(
    const float* A, const ushort* __restrict__ Wt,
    const float* __restrict__ bias, float* O, int M)
{
    constexpr int BM = 64;
    constexpr int HN = BN / 2;
    constexpr int NC = HN / 16;
    constexpr int C4 = K / 4;
    __shared__ ushort Als[BM * K];
    __shared__ ushort Wts[BN * BK];

    const int tid = threadIdx.x;
    const int lane = tid & 63, wid = tid >> 6;
    const int wr = wid >> 1, wc = wid & 1;
    const int lr = lane & 15, lk8 = (lane >> 4) * 8;
    const int row0 = blockIdx.x * BM;

    f32x4 acc[2][NC];
#pragma unroll
    for (int mr = 0; mr < 2; ++mr)
#pragma unroll
        for (int nc = 0; nc < NC; ++nc) acc[mr][nc] = (f32x4)0.f;

    for (int i = tid; i < BM * C4; i += 256) {
        int r = i / C4, c4 = i % C4;
        int row = row0 + r;
        float4 x = make_float4(0.f, 0.f, 0.f, 0.f);
        if (row < M) x = *(const float4*)(A + (size_t)row * K + c4 * 4);
        ushort4 o;
        o.x = f2b(x.x); o.y = f2b(x.y); o.z = f2b(x.z); o.w = f2b(x.w);
        int slot = (c4 >> 1) ^ (r & 7);
        *(ushort4*)&Als[r * K + slot * 8 + (c4 & 1) * 4] = o;
    }

    for (int ci = 0; ci < K / BK; ++ci) {
        if (ci) __syncthreads();
        constexpr int NL = BN * BK * 2 / (256 * 16);
        const ushort* wsrc = Wt + ci * (BN * BK);
#pragma unroll
        for (int it = 0; it < NL; ++it) {
            int off16 = it * 256 + tid;
            gld_lds16(&wsrc[off16 * 8], &Wts[off16 * 8]);
        }
        __syncthreads();

#pragma unroll
        for (int k0 = 0; k0 < BK; k0 += 32) {
            short8 a[2], bfr[NC];
#pragma unroll
            for (int mr = 0; mr < 2; ++mr) {
                int r = wr * 32 + mr * 16 + lr;
                int k = ci * BK + k0 + lk8;
                int slot = (k >> 3) ^ (r & 7);
                a[mr] = *(const short8*)&Als[r * K + slot * 8];
            }
#pragma unroll
            for (int nc = 0; nc < NC; ++nc) {
                int n = wc * HN + nc * 16 + lr;
                int kk = k0 + lk8;
                int slot = (kk >> 3) ^ (n & 7);
                bfr[nc] = *(const short8*)&Wts[n * BK + slot * 8];
            }
#pragma unroll
            for (int mr = 0; mr < 2; ++mr)
#pragma unroll
                for (int nc = 0; nc < NC; ++nc)
                    acc[mr][nc] = __builtin_amdgcn_mfma_f32_16x16x32_bf16(
                        a[mr], bfr[nc], acc[mr][nc], 0, 0, 0);
        }
    }

#pragma unroll
    for (int mr = 0; mr < 2; ++mr)
#pragma unroll
        for (int nc = 0; nc < NC; ++nc) {
            int col = wc * HN + nc * 16 + lr;
            float bv = bias[col];
#pragma unroll
            for (int r = 0; r < 4; ++r) {
                int row = row0 + wr * 32 + mr * 16 + (lane >> 4) * 4 + r;
                if (row < M)
                    O[(size_t)row * BN + col] = fmaxf(acc[mr][nc][r] + bv, 0.f);
            }
        }
}

// ---------------------------------------------------------------------------
extern "C" void kernel_launch(void* const* d_in, const int* in_sizes, int n_in,
                              void* d_out, int out_size, void* d_ws, size_t ws_size,
                              hipStream_t stream)
{
    const float* feat_c = (const float*)d_in[0];
    const float* feat_d = (const float*)d_in[1];
    const int* src_c = (const int*)d_in[2];
    const int* dst_c = (const int*)d_in[3];
    const int* src_d = (const int*)d_in[4];
    const int* dst_d = (const int*)d_in[5];
    const float* W_c = (const float*)d_in[6];
    const float* b_c = (const float*)d_in[7];
    const float* W_d = (const float*)d_in[8];
    const float* b_d = (const float*)d_in[9];

    const int D_c = in_sizes[7];          // 128
    const int D_d = in_sizes[9];          // 256
    const int N = in_sizes[0] / D_c;      // 50000
    const int E_c = in_sizes[2];
    const int E_d = in_sizes[4];

    float* out_c = (float*)d_out;
    float* out_d = (float*)d_out + (size_t)N * D_c;

    const int NBKT = (N + 255) >> 8;      // 196
    int capc = E_c / NBKT; capc += 8 * (int)sqrtf((float)capc) + 32; capc = (capc + 15) & ~15;
    int capd = E_d / NBKT; capd += 8 * (int)sqrtf((float)capd) + 32; capd = (capd + 15) & ~15;
    if (capc > CAPMAX) capc = CAPMAX;
    if (capd > CAPMAX) capd = CAPMAX;

    // workspace layout (ints unless noted)
    int* ws = (int*)d_ws;
    int* cnt_out_c = ws;                          // N
    int* cnt_out_d = ws + N;                      // N
    int* gf_cd = ws + 2 * (size_t)N;              // 256
    int* gf_cs = gf_cd + 256;                     // 256
    int* gf_dd = gf_cs + 256;                     // 256
    int* gf_ds = gf_dd + 256;                     // 256
    int* rs_c  = gf_ds + 256;                     // N
    int* dg_c  = rs_c + N;                        // N
    int* rs_d  = dg_c + N;                        // N
    int* dg_d  = rs_d + N;                        // N
    ushort* Wt_c = (ushort*)(dg_d + N);           // 128*128
    ushort* Wt_d = Wt_c + 16384;                  // 256*256
    int* dbuf_c = (int*)(Wt_d + 65536);           // NBKT*capc
    int* sbuf_c = dbuf_c + (size_t)NBKT * capc;   // NBKT*capc
    int* dbuf_d = sbuf_c + (size_t)NBKT * capc;   // NBKT*capd
    int* sbuf_d = dbuf_d + (size_t)NBKT * capd;   // NBKT*capd
    ushort* Xb_c = (ushort*)(sbuf_d + (size_t)NBKT * capd);  // N*128
    ushort* Xb_d = Xb_c + (size_t)N * D_c;        // N*256

    hipMemsetAsync(gf_cd, 0, 1024 * sizeof(int), stream);

    wprep_kernel<<<40, 256, 0, stream>>>(W_c, W_d, Wt_c, Wt_d);

    const int Rc = (E_c + RND - 1) / RND;   // 391
    const int Rd = (E_d + RND - 1) / RND;   // 196
    part_kernel<<<2 * (Rc + Rd), 256, 0, stream>>>(
        src_c, dst_c, E_c, Rc, src_d, dst_d, E_d, Rd,
        gf_cd, gf_cs, gf_dd, gf_ds,
        dbuf_c, sbuf_c, dbuf_d, sbuf_d, capc, capd);

    b2s_kernel<<<2 * NBKT, 256, 0, stream>>>(
        sbuf_c, gf_cs, capc, cnt_out_c,
        sbuf_d, gf_ds, capd, cnt_out_d, N, NBKT);

    int nbc = (N * (D_c / 4) + 255) / 256, nbd = (N * (D_d / 4) + 255) / 256;
    cast_kernel<<<nbc + nbd, 256, 0, stream>>>(feat_c, cnt_out_c, Xb_c,
                                               feat_d, cnt_out_d, Xb_d, N, nbc);

    b2d_kernel<<<2 * NBKT, 256, 0, stream>>>(
        dbuf_c, gf_cd, capc, rs_c, dg_c,
        dbuf_d, gf_dd, capd, rs_d, dg_d, N, NBKT);

    int abc = (N + 3) / 4;
    agg_kernel2<<<2 * abc, 256, 0, stream>>>(Xb_c, rs_c, dg_c, dbuf_c, out_c,
                                             Xb_d, rs_d, dg_d, dbuf_d, out_d, N, abc);

    int gb = (N + 63) / 64;
    gemm2_kernel<128, 128, 128><<<gb, 256, 0, stream>>>(out_c, Wt_c, b_c, out_c, N);
    gemm2_kernel<256, 256, 64><<<gb, 256, 0, stream>>>(out_d, Wt_d, b_d, out_d, N);
}